// Round 1
// baseline (271.089 us; speedup 1.0000x reference)
//
#include <hip/hip_runtime.h>
#include <math.h>

#define BB 4
#define TT 8192
#define DD 2048
#define KK 4096

// d_out layout (floats): selected_x | idx | scores | out
static constexpr long long OFF_SELX   = 0;
static constexpr long long OFF_IDX    = (long long)BB * KK * DD;          // 33554432
static constexpr long long OFF_SCORES = OFF_IDX + (long long)BB * KK;     // +16384
static constexpr long long OFF_OUT    = OFF_SCORES + (long long)BB * TT;  // +32768

__device__ __forceinline__ unsigned int f2key(float f) {
    unsigned int u = __float_as_uint(f);
    return (u & 0x80000000u) ? ~u : (u | 0x80000000u);
}

// ---------------- K1: scores[b,t] = dot(x[b,t,:], W) + entropy[b,t] ----------------
// one wave (64 lanes) per row; f64 accumulate; 4 waves per block
__global__ __launch_bounds__(256) void k_scores(const float* __restrict__ x,
                                                const float* __restrict__ ent,
                                                const float* __restrict__ W,
                                                float* __restrict__ scores) {
    int wave = threadIdx.x >> 6;
    int lane = threadIdx.x & 63;
    long long row = (long long)blockIdx.x * 4 + wave;  // b*TT + t
    const float4* xr = (const float4*)(x + row * DD);
    const float4* wr = (const float4*)W;
    double acc = 0.0;
#pragma unroll
    for (int j = 0; j < 8; ++j) {
        float4 a = xr[lane + 64 * j];
        float4 w = wr[lane + 64 * j];
        acc += (double)a.x * w.x + (double)a.y * w.y + (double)a.z * w.z + (double)a.w * w.w;
    }
#pragma unroll
    for (int m = 32; m >= 1; m >>= 1) acc += __shfl_xor(acc, m, 64);
    if (lane == 0) {
        float sdot = (float)acc;            // round like the f32 einsum result
        scores[row] = sdot + ent[row];      // then + entropy in f32
    }
}

// ---------------- K2: per-row MSB radix select of K-th largest key ----------------
__global__ __launch_bounds__(256) void k_select_thr(const float* __restrict__ scores,
                                                    unsigned int* __restrict__ thr_key,
                                                    int* __restrict__ n_take) {
    int b = blockIdx.x;
    const float* s = scores + (long long)b * TT;
    __shared__ unsigned int hist[256];
    __shared__ unsigned int s_prefix;
    __shared__ int s_remaining;
    if (threadIdx.x == 0) { s_prefix = 0u; s_remaining = KK; }
    __syncthreads();
    for (int p = 3; p >= 0; --p) {
        for (int i = threadIdx.x; i < 256; i += blockDim.x) hist[i] = 0u;
        __syncthreads();
        unsigned int mask = (p == 3) ? 0u : (0xFFFFFFFFu << ((p + 1) * 8));
        unsigned int prefix = s_prefix;
        for (int i = threadIdx.x; i < TT; i += blockDim.x) {
            unsigned int key = f2key(s[i]);
            if ((key & mask) == (prefix & mask))
                atomicAdd(&hist[(key >> (p * 8)) & 0xFFu], 1u);
        }
        __syncthreads();
        if (threadIdx.x == 0) {
            int rem = s_remaining;
            unsigned int cum = 0;
            int chosen = 0;
            for (int bin = 255; bin >= 0; --bin) {
                if ((int)(cum + hist[bin]) >= rem) { chosen = bin; break; }
                cum += hist[bin];
            }
            s_remaining = rem - (int)cum;                    // ties still needed
            s_prefix = prefix | ((unsigned int)chosen << (p * 8));
        }
        __syncthreads();
    }
    if (threadIdx.x == 0) { thr_key[b] = s_prefix; n_take[b] = s_remaining; }
}

// ---------------- K3: selection flags + prefix sums -> slots, idx output ----------------
__global__ __launch_bounds__(1024) void k_build_sel(const float* __restrict__ scores,
                                                    const unsigned int* __restrict__ thr_key,
                                                    const int* __restrict__ n_take,
                                                    int* __restrict__ sel_slot,
                                                    float* __restrict__ idx_out) {
    int b = blockIdx.x;
    const float* s = scores + (long long)b * TT;
    unsigned int thr = thr_key[b];
    int ntake = n_take[b];
    int tid = threadIdx.x;
    int base = tid * 8;
    unsigned int key[8];
#pragma unroll
    for (int j = 0; j < 8; ++j) key[j] = f2key(s[base + j]);

    __shared__ int lds[1024];
    // exclusive scan of per-thread eq counts
    int eqsum = 0;
#pragma unroll
    for (int j = 0; j < 8; ++j) eqsum += (key[j] == thr);
    lds[tid] = eqsum; __syncthreads();
    for (int off = 1; off < 1024; off <<= 1) {
        int t = (tid >= off) ? lds[tid - off] : 0;
        __syncthreads();
        lds[tid] += t;
        __syncthreads();
    }
    int eqrank = lds[tid] - eqsum;  // #eq with t' < base

    int sel[8]; int selsum = 0;
#pragma unroll
    for (int j = 0; j < 8; ++j) {
        int is_eq = (key[j] == thr);
        int take = (key[j] > thr) || (is_eq && (eqrank < ntake));
        eqrank += is_eq;
        sel[j] = take; selsum += take;
    }
    __syncthreads();
    lds[tid] = selsum; __syncthreads();
    for (int off = 1; off < 1024; off <<= 1) {
        int t = (tid >= off) ? lds[tid - off] : 0;
        __syncthreads();
        lds[tid] += t;
        __syncthreads();
    }
    int slot = lds[tid] - selsum;   // exclusive: #selected with t' < base
#pragma unroll
    for (int j = 0; j < 8; ++j) {
        int t = base + j;
        if (sel[j]) {
            sel_slot[(long long)b * TT + t] = slot;
            idx_out[(long long)b * KK + slot] = (float)t;  // buffer is float32
            slot++;
        } else {
            sel_slot[(long long)b * TT + t] = -1;
        }
    }
}

// ---------------- K4: out = x (+ sigmoid(score)*processed at sel); selected_x gather ----------------
__global__ __launch_bounds__(256) void k_emit(const float* __restrict__ x,
                                              const float* __restrict__ processed,
                                              const float* __restrict__ scores,
                                              const int* __restrict__ sel_slot,
                                              float* __restrict__ selx,
                                              float* __restrict__ outp) {
    long long row = blockIdx.x;                 // b*TT + t
    int b = (int)(row / TT);
    int slot = sel_slot[row];
    const float4* xr = (const float4*)(x + row * DD);
    float4* orow = (float4*)(outp + row * DD);
    if (slot >= 0) {
        float s = scores[row];
        float w = 1.0f / (1.0f + expf(-s));
        const float4* pr = (const float4*)(processed + ((long long)b * KK + slot) * DD);
        float4* sx = (float4*)(selx + ((long long)b * KK + slot) * DD);
#pragma unroll
        for (int k = 0; k < 2; ++k) {
            int i = threadIdx.x + k * 256;
            float4 v = xr[i];
            float4 p = pr[i];
            sx[i] = v;
            float4 o;
            o.x = v.x + p.x * w;
            o.y = v.y + p.y * w;
            o.z = v.z + p.z * w;
            o.w = v.w + p.w * w;
            orow[i] = o;
        }
    } else {
#pragma unroll
        for (int k = 0; k < 2; ++k) {
            int i = threadIdx.x + k * 256;
            orow[i] = xr[i];
        }
    }
}

extern "C" void kernel_launch(void* const* d_in, const int* in_sizes, int n_in,
                              void* d_out, int out_size, void* d_ws, size_t ws_size,
                              hipStream_t stream) {
    const float* x         = (const float*)d_in[0];
    const float* ent       = (const float*)d_in[1];
    const float* processed = (const float*)d_in[2];
    const float* W         = (const float*)d_in[3];

    float* outf   = (float*)d_out;
    float* selx   = outf + OFF_SELX;
    float* idxout = outf + OFF_IDX;
    float* scores = outf + OFF_SCORES;
    float* outp   = outf + OFF_OUT;

    unsigned int* thr_key = (unsigned int*)d_ws;            // [BB]
    int* n_take           = (int*)d_ws + BB;                // [BB]
    int* sel_slot         = (int*)d_ws + 2 * BB;            // [BB*TT]

    k_scores<<<dim3(BB * TT / 4), dim3(256), 0, stream>>>(x, ent, W, scores);
    k_select_thr<<<dim3(BB), dim3(256), 0, stream>>>(scores, thr_key, n_take);
    k_build_sel<<<dim3(BB), dim3(1024), 0, stream>>>(scores, thr_key, n_take, sel_slot, idxout);
    k_emit<<<dim3(BB * TT), dim3(256), 0, stream>>>(x, processed, scores, sel_slot, selx, outp);
}

// Round 2
// 214.281 us; speedup vs baseline: 1.2651x; 1.2651x over previous
//
#include <hip/hip_runtime.h>
#include <math.h>

#define BB 4
#define TT 8192
#define DD 2048
#define KK 4096

// d_out layout (floats): selected_x | idx | scores | out
static constexpr long long OFF_SELX   = 0;
static constexpr long long OFF_IDX    = (long long)BB * KK * DD;          // 33554432
static constexpr long long OFF_SCORES = OFF_IDX + (long long)BB * KK;     // +16384
static constexpr long long OFF_OUT    = OFF_SCORES + (long long)BB * TT;  // +32768

__device__ __forceinline__ unsigned int f2key(float f) {
    unsigned int u = __float_as_uint(f);
    return (u & 0x80000000u) ? ~u : (u | 0x80000000u);
}

// ---------------- K1: scores[b,t] = dot(x[b,t,:], W) + entropy[b,t] ----------------
// one wave (64 lanes) per row; f64 accumulate; 4 waves per block
__global__ __launch_bounds__(256) void k_scores(const float* __restrict__ x,
                                                const float* __restrict__ ent,
                                                const float* __restrict__ W,
                                                float* __restrict__ scores) {
    int wave = threadIdx.x >> 6;
    int lane = threadIdx.x & 63;
    long long row = (long long)blockIdx.x * 4 + wave;  // b*TT + t
    const float4* xr = (const float4*)(x + row * DD);
    const float4* wr = (const float4*)W;
    double acc = 0.0;
#pragma unroll
    for (int j = 0; j < 8; ++j) {
        float4 a = xr[lane + 64 * j];
        float4 w = wr[lane + 64 * j];
        acc += (double)a.x * w.x + (double)a.y * w.y + (double)a.z * w.z + (double)a.w * w.w;
    }
#pragma unroll
    for (int m = 32; m >= 1; m >>= 1) acc += __shfl_xor(acc, m, 64);
    if (lane == 0) {
        float sdot = (float)acc;            // round like the f32 einsum result
        scores[row] = sdot + ent[row];      // then + entropy in f32
    }
}

// ---------------- K2: fused radix-select + selection build (1 block/row, 1024 thr) ----
// keys live in registers for all passes; wave-shuffle scans, ~16 barriers total
__global__ __launch_bounds__(1024) void k_select(const float* __restrict__ scores,
                                                 int* __restrict__ sel_slot,
                                                 float* __restrict__ idx_out) {
    int b = blockIdx.x;
    const float* s = scores + (long long)b * TT;
    int tid  = threadIdx.x;
    int lane = tid & 63;
    int wid  = tid >> 6;  // 16 waves

    unsigned int key[8];
    {
        const float4* sv = (const float4*)(s + tid * 8);
        float4 a = sv[0], c = sv[1];
        key[0] = f2key(a.x); key[1] = f2key(a.y); key[2] = f2key(a.z); key[3] = f2key(a.w);
        key[4] = f2key(c.x); key[5] = f2key(c.y); key[6] = f2key(c.z); key[7] = f2key(c.w);
    }

    __shared__ unsigned int hist[256];
    __shared__ unsigned int s_prefix;
    __shared__ int s_rem;
    __shared__ int warp_tot[16];
    __shared__ int warp_off[16];

    if (tid == 0) { s_prefix = 0u; s_rem = KK; }

    for (int p = 3; p >= 0; --p) {
        if (tid < 256) hist[tid] = 0u;
        __syncthreads();                       // also covers s_prefix init on first pass
        unsigned int mask   = (p == 3) ? 0u : (0xFFFFFFFFu << ((p + 1) * 8));
        unsigned int prefix = s_prefix;
        int rem = s_rem;
#pragma unroll
        for (int j = 0; j < 8; ++j)
            if ((key[j] & mask) == (prefix & mask))
                atomicAdd(&hist[(key[j] >> (p * 8)) & 0xFFu], 1u);
        __syncthreads();
        if (tid < 64) {
            // lane l owns bins {255-4l, 254-4l, 253-4l, 252-4l} (descending order)
            unsigned int h0 = hist[255 - 4 * lane];
            unsigned int h1 = hist[254 - 4 * lane];
            unsigned int h2 = hist[253 - 4 * lane];
            unsigned int h3 = hist[252 - 4 * lane];
            unsigned int lsum = h0 + h1 + h2 + h3;
            unsigned int inc = lsum;
#pragma unroll
            for (int off = 1; off < 64; off <<= 1) {
                unsigned int n = __shfl_up(inc, off, 64);
                if (lane >= off) inc += n;
            }
            unsigned int cum = inc - lsum;     // keys in bins above my group
            unsigned int hh[4] = {h0, h1, h2, h3};
#pragma unroll
            for (int q = 0; q < 4; ++q) {
                int bin = 255 - 4 * lane - q;
                if ((int)cum < rem && (int)(cum + hh[q]) >= rem) {
                    s_prefix = prefix | ((unsigned int)bin << (p * 8));
                    s_rem = rem - (int)cum;
                }
                cum += hh[q];
            }
        }
        __syncthreads();
    }

    unsigned int thr = s_prefix;
    int ntake = s_rem;

    // ---- scan 1: exclusive prefix of per-thread eq counts ----
    int eq[8];
    int eqsum = 0;
#pragma unroll
    for (int j = 0; j < 8; ++j) { eq[j] = (key[j] == thr); eqsum += eq[j]; }
    int inc1 = eqsum;
#pragma unroll
    for (int off = 1; off < 64; off <<= 1) {
        int n = __shfl_up(inc1, off, 64);
        if (lane >= off) inc1 += n;
    }
    if (lane == 63) warp_tot[wid] = inc1;
    __syncthreads();
    if (tid < 16) {
        int v = warp_tot[tid];
        int i2 = v;
#pragma unroll
        for (int off = 1; off < 16; off <<= 1) {
            int n = __shfl_up(i2, off, 16);
            if (tid >= off) i2 += n;
        }
        warp_off[tid] = i2 - v;
    }
    __syncthreads();
    int eqrank = warp_off[wid] + inc1 - eqsum;

    // ---- selection decision ----
    int sel[8];
    int selsum = 0;
#pragma unroll
    for (int j = 0; j < 8; ++j) {
        int take = (key[j] > thr) || (eq[j] && (eqrank < ntake));
        eqrank += eq[j];
        sel[j] = take; selsum += take;
    }

    // ---- scan 2: exclusive prefix of per-thread sel counts ----
    int inc2 = selsum;
#pragma unroll
    for (int off = 1; off < 64; off <<= 1) {
        int n = __shfl_up(inc2, off, 64);
        if (lane >= off) inc2 += n;
    }
    if (lane == 63) warp_tot[wid] = inc2;
    __syncthreads();
    if (tid < 16) {
        int v = warp_tot[tid];
        int i2 = v;
#pragma unroll
        for (int off = 1; off < 16; off <<= 1) {
            int n = __shfl_up(i2, off, 16);
            if (tid >= off) i2 += n;
        }
        warp_off[tid] = i2 - v;
    }
    __syncthreads();
    int slot = warp_off[wid] + inc2 - selsum;

    // ---- writes ----
    int base = tid * 8;
    int ss[8];
#pragma unroll
    for (int j = 0; j < 8; ++j) {
        if (sel[j]) {
            ss[j] = slot;
            idx_out[(long long)b * KK + slot] = (float)(base + j);
            slot++;
        } else {
            ss[j] = -1;
        }
    }
    int4* dst = (int4*)(sel_slot + (long long)b * TT + base);
    dst[0] = make_int4(ss[0], ss[1], ss[2], ss[3]);
    dst[1] = make_int4(ss[4], ss[5], ss[6], ss[7]);
}

// ---------------- K3: out = x (+ sigmoid(score)*processed at sel); selected_x gather ----
__global__ __launch_bounds__(256) void k_emit(const float* __restrict__ x,
                                              const float* __restrict__ processed,
                                              const float* __restrict__ scores,
                                              const int* __restrict__ sel_slot,
                                              float* __restrict__ selx,
                                              float* __restrict__ outp) {
    long long row = blockIdx.x;                 // b*TT + t
    int b = (int)(row / TT);
    int slot = sel_slot[row];
    const float4* xr = (const float4*)(x + row * DD);
    float4* orow = (float4*)(outp + row * DD);
    if (slot >= 0) {
        float s = scores[row];
        float w = 1.0f / (1.0f + expf(-s));
        const float4* pr = (const float4*)(processed + ((long long)b * KK + slot) * DD);
        float4* sx = (float4*)(selx + ((long long)b * KK + slot) * DD);
#pragma unroll
        for (int k = 0; k < 2; ++k) {
            int i = threadIdx.x + k * 256;
            float4 v = xr[i];
            float4 p = pr[i];
            sx[i] = v;
            float4 o;
            o.x = v.x + p.x * w;
            o.y = v.y + p.y * w;
            o.z = v.z + p.z * w;
            o.w = v.w + p.w * w;
            orow[i] = o;
        }
    } else {
#pragma unroll
        for (int k = 0; k < 2; ++k) {
            int i = threadIdx.x + k * 256;
            orow[i] = xr[i];
        }
    }
}

extern "C" void kernel_launch(void* const* d_in, const int* in_sizes, int n_in,
                              void* d_out, int out_size, void* d_ws, size_t ws_size,
                              hipStream_t stream) {
    const float* x         = (const float*)d_in[0];
    const float* ent       = (const float*)d_in[1];
    const float* processed = (const float*)d_in[2];
    const float* W         = (const float*)d_in[3];

    float* outf   = (float*)d_out;
    float* selx   = outf + OFF_SELX;
    float* idxout = outf + OFF_IDX;
    float* scores = outf + OFF_SCORES;
    float* outp   = outf + OFF_OUT;

    int* sel_slot = (int*)d_ws;                 // [BB*TT]

    k_scores<<<dim3(BB * TT / 4), dim3(256), 0, stream>>>(x, ent, W, scores);
    k_select<<<dim3(BB), dim3(1024), 0, stream>>>(scores, sel_slot, idxout);
    k_emit<<<dim3(BB * TT), dim3(256), 0, stream>>>(x, processed, scores, sel_slot, selx, outp);
}

// Round 4
// 166.155 us; speedup vs baseline: 1.6315x; 1.2896x over previous
//
#include <hip/hip_runtime.h>
#include <math.h>

#define BB 4
#define TT 8192
#define DD 2048
#define KK 4096

typedef float f32x4 __attribute__((ext_vector_type(4)));

// d_out layout (floats): selected_x | idx | scores | out
static constexpr long long OFF_SELX   = 0;
static constexpr long long OFF_IDX    = (long long)BB * KK * DD;          // 33554432
static constexpr long long OFF_SCORES = OFF_IDX + (long long)BB * KK;     // +16384
static constexpr long long OFF_OUT    = OFF_SCORES + (long long)BB * TT;  // +32768

__device__ __forceinline__ unsigned int f2key(float f) {
    unsigned int u = __float_as_uint(f);
    return (u & 0x80000000u) ? ~u : (u | 0x80000000u);
}

// ---------------- K1: scores[b,t] = dot(x[b,t,:], W) + entropy[b,t] ----------------
// one wave (64 lanes) per row; f64 accumulate (2 chains); 4 waves per block
__global__ __launch_bounds__(256) void k_scores(const float* __restrict__ x,
                                                const float* __restrict__ ent,
                                                const float* __restrict__ W,
                                                float* __restrict__ scores) {
    int wave = threadIdx.x >> 6;
    int lane = threadIdx.x & 63;
    long long row = (long long)blockIdx.x * 4 + wave;  // b*TT + t
    const float4* xr = (const float4*)(x + row * DD);
    const float4* wr = (const float4*)W;
    double acc0 = 0.0, acc1 = 0.0;
#pragma unroll
    for (int j = 0; j < 8; j += 2) {
        float4 a0 = xr[lane + 64 * j];
        float4 w0 = wr[lane + 64 * j];
        float4 a1 = xr[lane + 64 * (j + 1)];
        float4 w1 = wr[lane + 64 * (j + 1)];
        acc0 += (double)a0.x * w0.x + (double)a0.y * w0.y + (double)a0.z * w0.z + (double)a0.w * w0.w;
        acc1 += (double)a1.x * w1.x + (double)a1.y * w1.y + (double)a1.z * w1.z + (double)a1.w * w1.w;
    }
    double acc = acc0 + acc1;
#pragma unroll
    for (int m = 32; m >= 1; m >>= 1) acc += __shfl_xor(acc, m, 64);
    if (lane == 0) {
        float sdot = (float)acc;            // round like the f32 einsum result
        scores[row] = sdot + ent[row];      // then + entropy in f32
    }
}

// ---------------- K2: fused radix-select + selection build (1 block/row, 1024 thr) ----
__global__ __launch_bounds__(1024) void k_select(const float* __restrict__ scores,
                                                 int* __restrict__ sel_slot,
                                                 float* __restrict__ idx_out) {
    int b = blockIdx.x;
    const float* s = scores + (long long)b * TT;
    int tid  = threadIdx.x;
    int lane = tid & 63;
    int wid  = tid >> 6;  // 16 waves

    unsigned int key[8];
    {
        const float4* sv = (const float4*)(s + tid * 8);
        float4 a = sv[0], c = sv[1];
        key[0] = f2key(a.x); key[1] = f2key(a.y); key[2] = f2key(a.z); key[3] = f2key(a.w);
        key[4] = f2key(c.x); key[5] = f2key(c.y); key[6] = f2key(c.z); key[7] = f2key(c.w);
    }

    __shared__ unsigned int hist[256];
    __shared__ unsigned int s_prefix;
    __shared__ int s_rem;
    __shared__ int warp_tot[16];
    __shared__ int warp_off[16];

    if (tid == 0) { s_prefix = 0u; s_rem = KK; }

    for (int p = 3; p >= 0; --p) {
        if (tid < 256) hist[tid] = 0u;
        __syncthreads();
        unsigned int mask   = (p == 3) ? 0u : (0xFFFFFFFFu << ((p + 1) * 8));
        unsigned int prefix = s_prefix;
        int rem = s_rem;
#pragma unroll
        for (int j = 0; j < 8; ++j)
            if ((key[j] & mask) == (prefix & mask))
                atomicAdd(&hist[(key[j] >> (p * 8)) & 0xFFu], 1u);
        __syncthreads();
        if (tid < 64) {
            unsigned int h0 = hist[255 - 4 * lane];
            unsigned int h1 = hist[254 - 4 * lane];
            unsigned int h2 = hist[253 - 4 * lane];
            unsigned int h3 = hist[252 - 4 * lane];
            unsigned int lsum = h0 + h1 + h2 + h3;
            unsigned int inc = lsum;
#pragma unroll
            for (int off = 1; off < 64; off <<= 1) {
                unsigned int n = __shfl_up(inc, off, 64);
                if (lane >= off) inc += n;
            }
            unsigned int cum = inc - lsum;
            unsigned int hh[4] = {h0, h1, h2, h3};
#pragma unroll
            for (int q = 0; q < 4; ++q) {
                int bin = 255 - 4 * lane - q;
                if ((int)cum < rem && (int)(cum + hh[q]) >= rem) {
                    s_prefix = prefix | ((unsigned int)bin << (p * 8));
                    s_rem = rem - (int)cum;
                }
                cum += hh[q];
            }
        }
        __syncthreads();
    }

    unsigned int thr = s_prefix;
    int ntake = s_rem;

    int eq[8];
    int eqsum = 0;
#pragma unroll
    for (int j = 0; j < 8; ++j) { eq[j] = (key[j] == thr); eqsum += eq[j]; }
    int inc1 = eqsum;
#pragma unroll
    for (int off = 1; off < 64; off <<= 1) {
        int n = __shfl_up(inc1, off, 64);
        if (lane >= off) inc1 += n;
    }
    if (lane == 63) warp_tot[wid] = inc1;
    __syncthreads();
    if (tid < 16) {
        int v = warp_tot[tid];
        int i2 = v;
#pragma unroll
        for (int off = 1; off < 16; off <<= 1) {
            int n = __shfl_up(i2, off, 16);
            if (tid >= off) i2 += n;
        }
        warp_off[tid] = i2 - v;
    }
    __syncthreads();
    int eqrank = warp_off[wid] + inc1 - eqsum;

    int sel[8];
    int selsum = 0;
#pragma unroll
    for (int j = 0; j < 8; ++j) {
        int take = (key[j] > thr) || (eq[j] && (eqrank < ntake));
        eqrank += eq[j];
        sel[j] = take; selsum += take;
    }

    int inc2 = selsum;
#pragma unroll
    for (int off = 1; off < 64; off <<= 1) {
        int n = __shfl_up(inc2, off, 64);
        if (lane >= off) inc2 += n;
    }
    if (lane == 63) warp_tot[wid] = inc2;
    __syncthreads();
    if (tid < 16) {
        int v = warp_tot[tid];
        int i2 = v;
#pragma unroll
        for (int off = 1; off < 16; off <<= 1) {
            int n = __shfl_up(i2, off, 16);
            if (tid >= off) i2 += n;
        }
        warp_off[tid] = i2 - v;
    }
    __syncthreads();
    int slot = warp_off[wid] + inc2 - selsum;

    int base = tid * 8;
    int ss[8];
#pragma unroll
    for (int j = 0; j < 8; ++j) {
        if (sel[j]) {
            ss[j] = slot;
            idx_out[(long long)b * KK + slot] = (float)(base + j);
            slot++;
        } else {
            ss[j] = -1;
        }
    }
    int4* dst = (int4*)(sel_slot + (long long)b * TT + base);
    dst[0] = make_int4(ss[0], ss[1], ss[2], ss[3]);
    dst[1] = make_int4(ss[4], ss[5], ss[6], ss[7]);
}

// ---------------- K3: out = x (+ sigmoid(score)*processed at sel); selected_x gather ----
// x loads NORMAL (want L3 hits from k_scores' streaming); processed loads and
// out/selx stores NON-TEMPORAL (zero reuse -> don't evict x from L3).
__global__ __launch_bounds__(256) void k_emit(const float* __restrict__ x,
                                              const float* __restrict__ processed,
                                              const float* __restrict__ scores,
                                              const int* __restrict__ sel_slot,
                                              float* __restrict__ selx,
                                              float* __restrict__ outp) {
    long long row = blockIdx.x;                 // b*TT + t
    int b = (int)(row / TT);
    int slot = sel_slot[row];
    const f32x4* xr = (const f32x4*)(x + row * DD);
    f32x4* orow = (f32x4*)(outp + row * DD);
    if (slot >= 0) {
        float s = scores[row];
        float w = 1.0f / (1.0f + expf(-s));
        const f32x4* pr = (const f32x4*)(processed + ((long long)b * KK + slot) * DD);
        f32x4* sx = (f32x4*)(selx + ((long long)b * KK + slot) * DD);
#pragma unroll
        for (int k = 0; k < 2; ++k) {
            int i = threadIdx.x + k * 256;
            f32x4 v = xr[i];
            f32x4 p = __builtin_nontemporal_load(&pr[i]);
            __builtin_nontemporal_store(v, &sx[i]);
            f32x4 o = v + p * w;
            __builtin_nontemporal_store(o, &orow[i]);
        }
    } else {
#pragma unroll
        for (int k = 0; k < 2; ++k) {
            int i = threadIdx.x + k * 256;
            f32x4 v = xr[i];
            __builtin_nontemporal_store(v, &orow[i]);
        }
    }
}

extern "C" void kernel_launch(void* const* d_in, const int* in_sizes, int n_in,
                              void* d_out, int out_size, void* d_ws, size_t ws_size,
                              hipStream_t stream) {
    const float* x         = (const float*)d_in[0];
    const float* ent       = (const float*)d_in[1];
    const float* processed = (const float*)d_in[2];
    const float* W         = (const float*)d_in[3];

    float* outf   = (float*)d_out;
    float* selx   = outf + OFF_SELX;
    float* idxout = outf + OFF_IDX;
    float* scores = outf + OFF_SCORES;
    float* outp   = outf + OFF_OUT;

    int* sel_slot = (int*)d_ws;                 // [BB*TT]

    k_scores<<<dim3(BB * TT / 4), dim3(256), 0, stream>>>(x, ent, W, scores);
    k_select<<<dim3(BB), dim3(1024), 0, stream>>>(scores, sel_slot, idxout);
    k_emit<<<dim3(BB * TT), dim3(256), 0, stream>>>(x, processed, scores, sel_slot, selx, outp);
}

// Round 5
// 165.020 us; speedup vs baseline: 1.6428x; 1.0069x over previous
//
#include <hip/hip_runtime.h>
#include <math.h>

#define BB 4
#define TT 8192
#define DD 2048
#define KK 4096
#define NROWS (BB * TT)

typedef float f32x4 __attribute__((ext_vector_type(4)));

// d_out layout (floats): selected_x | idx | scores | out
static constexpr long long OFF_SELX   = 0;
static constexpr long long OFF_IDX    = (long long)BB * KK * DD;          // 33554432
static constexpr long long OFF_SCORES = OFF_IDX + (long long)BB * KK;     // +16384
static constexpr long long OFF_OUT    = OFF_SCORES + (long long)BB * TT;  // +32768

__device__ __forceinline__ unsigned int f2key(float f) {
    unsigned int u = __float_as_uint(f);
    return (u & 0x80000000u) ? ~u : (u | 0x80000000u);
}

// ---------------- K1: scores[b,t] = dot(x[b,t,:], W) + entropy[b,t] ----------------
// one wave (64 lanes) per row; f64 accumulate (2 chains); 4 waves per block
__global__ __launch_bounds__(256) void k_scores(const float* __restrict__ x,
                                                const float* __restrict__ ent,
                                                const float* __restrict__ W,
                                                float* __restrict__ scores) {
    int wave = threadIdx.x >> 6;
    int lane = threadIdx.x & 63;
    long long row = (long long)blockIdx.x * 4 + wave;  // b*TT + t
    const float4* xr = (const float4*)(x + row * DD);
    const float4* wr = (const float4*)W;
    double acc0 = 0.0, acc1 = 0.0;
#pragma unroll
    for (int j = 0; j < 8; j += 2) {
        float4 a0 = xr[lane + 64 * j];
        float4 w0 = wr[lane + 64 * j];
        float4 a1 = xr[lane + 64 * (j + 1)];
        float4 w1 = wr[lane + 64 * (j + 1)];
        acc0 += (double)a0.x * w0.x + (double)a0.y * w0.y + (double)a0.z * w0.z + (double)a0.w * w0.w;
        acc1 += (double)a1.x * w1.x + (double)a1.y * w1.y + (double)a1.z * w1.z + (double)a1.w * w1.w;
    }
    double acc = acc0 + acc1;
#pragma unroll
    for (int m = 32; m >= 1; m >>= 1) acc += __shfl_xor(acc, m, 64);
    if (lane == 0) {
        float sdot = (float)acc;            // round like the f32 einsum result
        scores[row] = sdot + ent[row];      // then + entropy in f32
    }
}

// ---------------- K2: fused radix-select + selection build (1 block/row, 1024 thr) ----
__global__ __launch_bounds__(1024) void k_select(const float* __restrict__ scores,
                                                 int* __restrict__ sel_slot,
                                                 float* __restrict__ idx_out) {
    int b = blockIdx.x;
    const float* s = scores + (long long)b * TT;
    int tid  = threadIdx.x;
    int lane = tid & 63;
    int wid  = tid >> 6;  // 16 waves

    unsigned int key[8];
    {
        const float4* sv = (const float4*)(s + tid * 8);
        float4 a = sv[0], c = sv[1];
        key[0] = f2key(a.x); key[1] = f2key(a.y); key[2] = f2key(a.z); key[3] = f2key(a.w);
        key[4] = f2key(c.x); key[5] = f2key(c.y); key[6] = f2key(c.z); key[7] = f2key(c.w);
    }

    __shared__ unsigned int hist[256];
    __shared__ unsigned int s_prefix;
    __shared__ int s_rem;
    __shared__ int warp_tot[16];
    __shared__ int warp_off[16];

    if (tid == 0) { s_prefix = 0u; s_rem = KK; }

    for (int p = 3; p >= 0; --p) {
        if (tid < 256) hist[tid] = 0u;
        __syncthreads();
        unsigned int mask   = (p == 3) ? 0u : (0xFFFFFFFFu << ((p + 1) * 8));
        unsigned int prefix = s_prefix;
        int rem = s_rem;
#pragma unroll
        for (int j = 0; j < 8; ++j)
            if ((key[j] & mask) == (prefix & mask))
                atomicAdd(&hist[(key[j] >> (p * 8)) & 0xFFu], 1u);
        __syncthreads();
        if (tid < 64) {
            unsigned int h0 = hist[255 - 4 * lane];
            unsigned int h1 = hist[254 - 4 * lane];
            unsigned int h2 = hist[253 - 4 * lane];
            unsigned int h3 = hist[252 - 4 * lane];
            unsigned int lsum = h0 + h1 + h2 + h3;
            unsigned int inc = lsum;
#pragma unroll
            for (int off = 1; off < 64; off <<= 1) {
                unsigned int n = __shfl_up(inc, off, 64);
                if (lane >= off) inc += n;
            }
            unsigned int cum = inc - lsum;
            unsigned int hh[4] = {h0, h1, h2, h3};
#pragma unroll
            for (int q = 0; q < 4; ++q) {
                int bin = 255 - 4 * lane - q;
                if ((int)cum < rem && (int)(cum + hh[q]) >= rem) {
                    s_prefix = prefix | ((unsigned int)bin << (p * 8));
                    s_rem = rem - (int)cum;
                }
                cum += hh[q];
            }
        }
        __syncthreads();
    }

    unsigned int thr = s_prefix;
    int ntake = s_rem;

    int eq[8];
    int eqsum = 0;
#pragma unroll
    for (int j = 0; j < 8; ++j) { eq[j] = (key[j] == thr); eqsum += eq[j]; }
    int inc1 = eqsum;
#pragma unroll
    for (int off = 1; off < 64; off <<= 1) {
        int n = __shfl_up(inc1, off, 64);
        if (lane >= off) inc1 += n;
    }
    if (lane == 63) warp_tot[wid] = inc1;
    __syncthreads();
    if (tid < 16) {
        int v = warp_tot[tid];
        int i2 = v;
#pragma unroll
        for (int off = 1; off < 16; off <<= 1) {
            int n = __shfl_up(i2, off, 16);
            if (tid >= off) i2 += n;
        }
        warp_off[tid] = i2 - v;
    }
    __syncthreads();
    int eqrank = warp_off[wid] + inc1 - eqsum;

    int sel[8];
    int selsum = 0;
#pragma unroll
    for (int j = 0; j < 8; ++j) {
        int take = (key[j] > thr) || (eq[j] && (eqrank < ntake));
        eqrank += eq[j];
        sel[j] = take; selsum += take;
    }

    int inc2 = selsum;
#pragma unroll
    for (int off = 1; off < 64; off <<= 1) {
        int n = __shfl_up(inc2, off, 64);
        if (lane >= off) inc2 += n;
    }
    if (lane == 63) warp_tot[wid] = inc2;
    __syncthreads();
    if (tid < 16) {
        int v = warp_tot[tid];
        int i2 = v;
#pragma unroll
        for (int off = 1; off < 16; off <<= 1) {
            int n = __shfl_up(i2, off, 16);
            if (tid >= off) i2 += n;
        }
        warp_off[tid] = i2 - v;
    }
    __syncthreads();
    int slot = warp_off[wid] + inc2 - selsum;

    int base = tid * 8;
    int ss[8];
#pragma unroll
    for (int j = 0; j < 8; ++j) {
        if (sel[j]) {
            ss[j] = slot;
            idx_out[(long long)b * KK + slot] = (float)(base + j);
            slot++;
        } else {
            ss[j] = -1;
        }
    }
    int4* dst = (int4*)(sel_slot + (long long)b * TT + base);
    dst[0] = make_int4(ss[0], ss[1], ss[2], ss[3]);
    dst[1] = make_int4(ss[4], ss[5], ss[6], ss[7]);
}

// ---------------- K3: out = x (+ sigmoid(score)*processed at sel); selected_x gather ----
// REVERSE row order: k_scores installed x into L3 front-to-back; x == L3 size,
// so reading back-to-front starts on the freshest lines and follows install
// order, avoiding the LRU wrap-around thrash of a front-to-front re-read.
// 512 threads/block, one float4 per thread per row.
__global__ __launch_bounds__(512) void k_emit(const float* __restrict__ x,
                                              const float* __restrict__ processed,
                                              const float* __restrict__ scores,
                                              const int* __restrict__ sel_slot,
                                              float* __restrict__ selx,
                                              float* __restrict__ outp) {
    long long row = (long long)(NROWS - 1) - blockIdx.x;   // reverse traversal
    int b = (int)(row / TT);
    int slot = sel_slot[row];
    int i = threadIdx.x;
    const f32x4* xr = (const f32x4*)(x + row * DD);
    f32x4* orow = (f32x4*)(outp + row * DD);
    if (slot >= 0) {
        float s = scores[row];
        float w = 1.0f / (1.0f + expf(-s));
        const f32x4* pr = (const f32x4*)(processed + ((long long)b * KK + slot) * DD);
        f32x4* sx = (f32x4*)(selx + ((long long)b * KK + slot) * DD);
        f32x4 v = xr[i];
        f32x4 p = __builtin_nontemporal_load(&pr[i]);
        __builtin_nontemporal_store(v, &sx[i]);
        f32x4 o = v + p * w;
        __builtin_nontemporal_store(o, &orow[i]);
    } else {
        f32x4 v = xr[i];
        __builtin_nontemporal_store(v, &orow[i]);
    }
}

extern "C" void kernel_launch(void* const* d_in, const int* in_sizes, int n_in,
                              void* d_out, int out_size, void* d_ws, size_t ws_size,
                              hipStream_t stream) {
    const float* x         = (const float*)d_in[0];
    const float* ent       = (const float*)d_in[1];
    const float* processed = (const float*)d_in[2];
    const float* W         = (const float*)d_in[3];

    float* outf   = (float*)d_out;
    float* selx   = outf + OFF_SELX;
    float* idxout = outf + OFF_IDX;
    float* scores = outf + OFF_SCORES;
    float* outp   = outf + OFF_OUT;

    int* sel_slot = (int*)d_ws;                 // [BB*TT]

    k_scores<<<dim3(BB * TT / 4), dim3(256), 0, stream>>>(x, ent, W, scores);
    k_select<<<dim3(BB), dim3(1024), 0, stream>>>(scores, sel_slot, idxout);
    k_emit<<<dim3(NROWS), dim3(512), 0, stream>>>(x, processed, scores, sel_slot, selx, outp);
}